// Round 7
// baseline (209.551 us; speedup 1.0000x reference)
//
#include <hip/hip_runtime.h>

typedef _Float16 f16;
typedef __attribute__((ext_vector_type(4))) _Float16 f16x4;
typedef __attribute__((ext_vector_type(8))) _Float16 f16x8;
typedef __attribute__((ext_vector_type(4))) float f32x4;
typedef __attribute__((ext_vector_type(16))) float f32x16;
typedef unsigned int u32;

#define BB 32
#define LL 1024
#define DD 256

#define VMCNT(N) asm volatile("s_waitcnt vmcnt(" #N ")" ::: "memory")
#define LGKMCNT0 asm volatile("s_waitcnt lgkmcnt(0)" ::: "memory")

// async global->LDS, 16B per lane, dst = ldsbase + lane*16 (wave-uniform base)
__device__ __forceinline__ void async_copy16(const f16* g, f16* l) {
  __builtin_amdgcn_global_load_lds(
      (const __attribute__((address_space(1))) u32*)(const void*)g,
      (__attribute__((address_space(3))) u32*)(void*)l, 16, 0, 0);
}

// pack two f32 -> f16x2 in a u32 (v_cvt_pkrtz_f16_f32)
__device__ __forceinline__ u32 pack_pkrtz(float a, float b) {
  auto pk = __builtin_amdgcn_cvt_pkrtz(a, b);  // __fp16 ext_vector(2)
  u32 w;
  __builtin_memcpy(&w, &pk, 4);
  return w;
}

// ===========================================================================
// Scratch layouts (fragment-order, baked into DRAM):
//   F  [b][T=q>>5][s=d>>4][half=(d>>3)&1][l32=q&31][j=d&7]      (8192 f16/tile)
//   Vt [b][T=q>>5][t=d>>5][qh=(q>>4)&1][half=(q>>3)&1][l32=d&31][j=q&7]
//   WtF[N=n>>5][s=k>>4][half=(k>>3)&1][l32=n&31][j=k&7]
// Every producer store and consumer DMA is a linear 1-KB wave transaction;
// every LDS fragment read is &buf[frag*512 + lane*8] (lane-linear, conflict-
// free); flash Q / proj W fragment loads from global are contiguous 1 KB.
// ===========================================================================

// ---------------------------------------------------------------------------
// W[k][n] fp32 -> WtF fragment-order f16. 8 blocks (one per 32-col N-tile).
// ---------------------------------------------------------------------------
__global__ __launch_bounds__(256) void w_to_frag(const float* __restrict__ W,
                                                 f16* __restrict__ WtF) {
  __shared__ float T32[256][33];
  const int tid = threadIdx.x;
  const int N = blockIdx.x;
  const int nn = tid & 31, kr = tid >> 5;
#pragma unroll
  for (int p = 0; p < 32; ++p) {
    int k = p * 8 + kr;
    T32[k][nn] = W[(size_t)k * 256 + N * 32 + nn];
  }
  __syncthreads();
  const int wv = tid >> 6, lane = tid & 63;
  const int l32 = lane & 31, half = lane >> 5;
#pragma unroll
  for (int i = 0; i < 4; ++i) {
    int s = wv * 4 + i;
    f16x8 ov;
#pragma unroll
    for (int j = 0; j < 8; ++j) ov[j] = (f16)T32[s * 16 + half * 8 + j][l32];
    *(f16x8*)&WtF[(size_t)N * 8192 + s * 512 + lane * 8] = ov;
  }
}

// ---------------------------------------------------------------------------
// Projection: F = tanh(A @ W) + V^T emit, both in fragment-order layouts.
// (unchanged from R5/R6 -- flash fix this round for clean attribution)
// ---------------------------------------------------------------------------
__global__ __launch_bounds__(256, 3) void proj_mfma(
    const float* __restrict__ Pin, const float* __restrict__ Hin,
    const f16* __restrict__ WtF, f16* __restrict__ Fp, f16* __restrict__ Fh,
    f16* __restrict__ Vtp, f16* __restrict__ Vth) {
  __shared__ f16 As[64][264];  // 33 KB; 16-B aligned rows
  const int tid = threadIdx.x;
  const int wv = tid >> 6, lane = tid & 63;
  const int l32 = lane & 31, half = lane >> 5;
  const int wm = wv >> 1, wn = wv & 1;
  const float* A = blockIdx.z ? Hin : Pin;
  f16* F = blockIdx.z ? Fh : Fp;
  f16* VtO = blockIdx.z ? Vth : Vtp;
  const int m0 = blockIdx.x * 64;
  const int T0 = m0 >> 5;  // global tile index (= b*32 + local tile)

  // stage full A tile (64 x 256) fp32 -> f16, coalesced rows
  {
    const int r = tid >> 4;         // 0..15
    const int c4 = (tid & 15) * 4;  // 0..60
#pragma unroll
    for (int pp = 0; pp < 4; ++pp)
#pragma unroll
      for (int ch = 0; ch < 4; ++ch) {
        float4 v =
            *(const float4*)&A[(size_t)(m0 + r + pp * 16) * 256 + ch * 64 + c4];
        f16x4 h4;
        h4[0] = (f16)v.x; h4[1] = (f16)v.y; h4[2] = (f16)v.z; h4[3] = (f16)v.w;
        *(f16x4*)&As[r + pp * 16][ch * 64 + c4] = h4;
      }
  }
  __syncthreads();

  // hoist all 16 A-frags (32x32x16: m = wm*32+l32, k = ks*16+half*8+j)
  f16x8 af[16];
#pragma unroll
  for (int ks = 0; ks < 16; ++ks)
    af[ks] = *(const f16x8*)&As[wm * 32 + l32][ks * 16 + half * 8];

  // V^T emit (raw converted A), fragment-order: 8 linear 1-KB stores/wave
  {
#pragma unroll
    for (int i = 0; i < 8; ++i) {
      int idx = wv * 8 + i;               // 0..31
      int Tl = idx >> 4;                  // 0..1
      int t = (idx >> 1) & 7;             // 0..7 (d group)
      int qh = idx & 1;                   // 0..1 (q group)
      int qb = Tl * 32 + qh * 16 + half * 8;
      f16x8 ov;
#pragma unroll
      for (int j = 0; j < 8; ++j) ov[j] = As[qb + j][t * 32 + l32];
      *(f16x8*)&VtO[(size_t)(T0 + Tl) * 8192 + t * 1024 + qh * 512 +
                    half * 256 + l32 * 8] = ov;
    }
  }
  __syncthreads();  // all As reads done before tanh-bounce overwrite

  // nc loop: W frags contiguous from L2, MFMA, tanh -> As bounce (no barriers)
#pragma unroll
  for (int nc = 0; nc < 4; ++nc) {
    f32x16 acc = (f32x16)(0.f);
#pragma unroll
    for (int ks = 0; ks < 16; ++ks) {
      f16x8 wf = *(const f16x8*)&WtF[(size_t)nc * 16384 + wn * 8192 +
                                     ks * 512 + lane * 8];
      acc = __builtin_amdgcn_mfma_f32_32x32x16_f16(af[ks], wf, acc, 0, 0, 0);
    }
#pragma unroll
    for (int r = 0; r < 16; ++r) {
      float xv = acc[r];
      float e2 = __expf(2.f * xv);
      float th = 1.f - 2.f / (e2 + 1.f);
      As[wm * 32 + (r & 3) + 8 * (r >> 2) + 4 * half]
        [nc * 64 + wn * 32 + l32] = (f16)th;
    }
  }
  __syncthreads();

  // F store, fragment-order: 8 linear 1-KB stores/wave
#pragma unroll
  for (int i = 0; i < 8; ++i) {
    int idx = wv * 8 + i;  // 0..31
    int Tl = idx >> 4;     // 0..1
    int s = idx & 15;      // 0..15
    f16x8 ov = *(const f16x8*)&As[Tl * 32 + l32][s * 16 + half * 8];
    *(f16x8*)&F[(size_t)(T0 + Tl) * 8192 + s * 512 + half * 256 + l32 * 8] =
        ov;
  }
}

// ---------------------------------------------------------------------------
// Flash alignment, 32x32x16 MFMA, transposed formulation.
// R7: 8-wave blocks (halved L3 staging traffic, kept) + FULL-TILE prefetch
// distance restored (R6 bug: V issued at end of iter, waited at next top ->
// zero distance). Per body: stage(it+2) FIRST (dest buffers retired by prev
// end-barrier), vmcnt(4) waits only tile it+1 (issued one full body ago),
// then qk(it+1) || softmax(it) || pv(it) -- deferred softmax/PV makes the
// three phases mutually independent (MFMA chain latency hides under PV and
// softmax VALU). Deferred PV requires V(it..it+2) live -> V TRIPLE buffer.
// LDS: K dbuf 32 KB + V tribuf 48 KB = 80 KB.
// ---------------------------------------------------------------------------
__global__ __launch_bounds__(512, 2) void flash_mfma(
    const f16* __restrict__ Fpm, const f16* __restrict__ Fhm,
    const f16* __restrict__ Vth, const f16* __restrict__ Vtp,
    float* __restrict__ Out) {
  __shared__ f16 SMEM[5][8192];  // [0..1] K dbuf, [2..4] V tribuf (80 KB)

  const int tid = threadIdx.x;
  const int wv = tid >> 6, lane = tid & 63;
  const int l32 = lane & 31, half = lane >> 5;

  const f16* Fq = Fpm;
  const f16* Fk = Fhm;
  const f16* Vt = Vth;
  float* O = Out;
  if (blockIdx.y) { Fq = Fhm; Fk = Fpm; Vt = Vtp; O = Out + (size_t)BB * LL * DD; }

  // XCD swizzle: all 4 p-blocks of one batch share x%8 (one XCD residue).
  const int x = blockIdx.x;
  const int b = ((x >> 5) << 3) | (x & 7);
  const int pblk = (x >> 3) & 3;
  const int p0 = pblk * 256 + wv * 32;
  const int p = p0 + l32;  // this lane's p-column

  const f16* Fq_b = Fq + (size_t)b * LL * DD;
  const f16* Fk_b = Fk + (size_t)b * LL * DD;
  const f16* Vt_b = Vt + (size_t)b * LL * DD;

  // Q fragments (B-operand): n=p, k=s*16+half*8+j; contiguous 1 KB per wave
  f16x8 qf[16];
  {
    const f16* qt = Fq_b + (size_t)(p >> 5) * 8192 + half * 256 + (p & 31) * 8;
#pragma unroll
    for (int s = 0; s < 16; ++s) qf[s] = *(const f16x8*)&qt[s * 512];
  }

  float m_run = -1e30f, l_run = 0.f;
  f32x16 o[8];
#pragma unroll
  for (int t = 0; t < 8; ++t) o[t] = (f32x16)(0.f);

  // wave wv stages its 1-KB slices of K and V (2 instr each per tile)
  auto stage_K = [&](int slot, int T) {
    const f16* kt = Fk_b + (size_t)T * 8192 + wv * 1024 + lane * 8;
    async_copy16(kt, &SMEM[slot][wv * 1024]);
    async_copy16(kt + 512, &SMEM[slot][wv * 1024 + 512]);
  };
  auto stage_V = [&](int slot, int T) {
    const f16* vt = Vt_b + (size_t)T * 8192 + wv * 1024 + lane * 8;
    async_copy16(vt, &SMEM[2 + slot][wv * 1024]);
    async_copy16(vt + 512, &SMEM[2 + slot][wv * 1024 + 512]);
  };

  // QK^T: 16-MFMA chain; result consumed one body later (latency hidden)
  auto qk16 = [&](int slot) {
    f32x16 S = (f32x16)(0.f);
    __builtin_amdgcn_s_setprio(1);
#pragma unroll
    for (int s = 0; s < 16; ++s) {
      f16x8 kf = *(const f16x8*)&SMEM[slot][s * 512 + lane * 8];
      S = __builtin_amdgcn_mfma_f32_32x32x16_f16(kf, qf[s], S, 0, 0, 0);
    }
    __builtin_amdgcn_s_setprio(0);
    return S;
  };

  // softmax(S) -> pf[2] B-frags; updates m_run/l_run and rescales o
  f16x8 pf[2];
  auto softmax_pack = [&](const f32x16& S) {
    float mt = S[0];
#pragma unroll
    for (int r = 1; r < 16; ++r) mt = fmaxf(mt, S[r]);
    mt = fmaxf(mt, __shfl_xor(mt, 32, 64));
    const bool keep = __all((int)(mt - m_run <= 8.0f)) != 0;  // defer-max
    const float mn = keep ? m_run : fmaxf(m_run, mt);
    float pe[16];
    float ts = 0.f;
#pragma unroll
    for (int r = 0; r < 16; ++r) {
      pe[r] = __expf(S[r] - mn);
      ts += pe[r];
    }
    ts += __shfl_xor(ts, 32, 64);
    if (!keep) {
      const float alpha = __expf(m_run - mn);
      l_run *= alpha;
      m_run = mn;
#pragma unroll
      for (int t = 0; t < 8; ++t)
#pragma unroll
        for (int r = 0; r < 16; ++r) o[t][r] *= alpha;
    }
    l_run += ts;

    u32 pw[8];
#pragma unroll
    for (int i = 0; i < 8; ++i) pw[i] = pack_pkrtz(pe[2 * i], pe[2 * i + 1]);
    u32 rc[4];
    {
      u32 s0 = half ? pw[0] : pw[2];
      u32 s1 = half ? pw[1] : pw[3];
      u32 s2 = half ? pw[4] : pw[6];
      u32 s3 = half ? pw[5] : pw[7];
      rc[0] = (u32)__shfl_xor((int)s0, 32, 64);
      rc[1] = (u32)__shfl_xor((int)s1, 32, 64);
      rc[2] = (u32)__shfl_xor((int)s2, 32, 64);
      rc[3] = (u32)__shfl_xor((int)s3, 32, 64);
    }
#pragma unroll
    for (int h = 0; h < 2; ++h) {
      u32 tmp[4];
      tmp[0] = half ? rc[2 * h] : pw[4 * h];
      tmp[1] = half ? rc[2 * h + 1] : pw[4 * h + 1];
      tmp[2] = half ? pw[4 * h + 2] : rc[2 * h];
      tmp[3] = half ? pw[4 * h + 3] : rc[2 * h + 1];
      __builtin_memcpy(&pf[h], tmp, 16);
    }
  };

  auto pv = [&](int slot) {
    __builtin_amdgcn_s_setprio(1);
#pragma unroll
    for (int t = 0; t < 8; ++t) {
      f16x8 v0 = *(const f16x8*)&SMEM[2 + slot][t * 1024 + lane * 8];
      o[t] = __builtin_amdgcn_mfma_f32_32x32x16_f16(v0, pf[0], o[t], 0, 0, 0);
      f16x8 v1 = *(const f16x8*)&SMEM[2 + slot][t * 1024 + 512 + lane * 8];
      o[t] = __builtin_amdgcn_mfma_f32_32x32x16_f16(v1, pf[1], o[t], 0, 0, 0);
    }
    __builtin_amdgcn_s_setprio(0);
  };

  // prologue: tiles 0 and 1 fully in flight; wait tile 0, leave tile 1 going
  stage_K(0, 0);
  stage_V(0, 0);
  stage_K(1, 1);
  stage_V(1, 1);
  VMCNT(4);
  __builtin_amdgcn_sched_barrier(0);
  __builtin_amdgcn_s_barrier();
  f32x16 Scur = qk16(0);  // S(0)

  // body(it): stage(it+2); wait tile it+1; qk(it+1) || sm(it) || pv(it)
  for (int it = 0; it < 31; ++it) {
    if (it < 30) {
      stage_K(it & 1, it + 2);        // K slot (it+2)&1 == it&1; K(it) retired
      stage_V((it + 2) % 3, it + 2);  // V slot holds V(it-1), retired
      VMCNT(4);                       // own tile(it+1) loads landed
    } else {
      VMCNT(0);                       // drain: tile 31 landed
    }
    __builtin_amdgcn_sched_barrier(0);
    __builtin_amdgcn_s_barrier();     // everyone's tile(it+1) landed
    f32x16 Snext = qk16((it + 1) & 1);  // MFMA pipe
    softmax_pack(Scur);                 // VALU, independent of qk
    pv(it % 3);                         // MFMA, independent accumulators
    __builtin_amdgcn_s_barrier();       // body(it) reads retired
    Scur = Snext;
  }
  // tail: tile 31
  softmax_pack(Scur);
  pv(31 % 3);
  __syncthreads();  // all waves done with SMEM before epilogue overlay

  // epilogue: per 32x32 chunk, transpose via per-wave LDS tile (stride 36:
  // bank-balanced both sides), then 8 rows x 128B contiguous global stores.
  const float inv = 1.f / l_run;
  float* Tw = (float*)&SMEM[0][0] + wv * (32 * 36);  // 8 waves x 4.5 KB = 36 KB
  float* Ob = O + (size_t)b * LL * DD;
#pragma unroll
  for (int t = 0; t < 8; ++t) {
#pragma unroll
    for (int g = 0; g < 4; ++g) {
      int C = 2 * g + half;  // chunk idx 0..7 <-> global col t*32 + C*4
      f32x4 v;
      v[0] = o[t][4 * g + 0] * inv;
      v[1] = o[t][4 * g + 1] * inv;
      v[2] = o[t][4 * g + 2] * inv;
      v[3] = o[t][4 * g + 3] * inv;
      *(f32x4*)&Tw[l32 * 36 + C * 4] = v;
    }
    LGKMCNT0;
#pragma unroll
    for (int pass = 0; pass < 4; ++pass) {
      int row = pass * 8 + (lane >> 3);
      int Cr = lane & 7;
      f32x4 v = *(const f32x4*)&Tw[row * 36 + Cr * 4];
      *(f32x4*)&Ob[(size_t)(p0 + row) * DD + t * 32 + Cr * 4] = v;
    }
    LGKMCNT0;  // reads of this t done before next t's writes
  }
}

// ---------------------------------------------------------------------------
extern "C" void kernel_launch(void* const* d_in, const int* in_sizes, int n_in,
                              void* d_out, int out_size, void* d_ws,
                              size_t ws_size, hipStream_t stream) {
  const float* premises = (const float*)d_in[0];    // [32,1024,256] fp32
  const float* hypotheses = (const float*)d_in[1];  // [32,1024,256] fp32
  const float* W = (const float*)d_in[2];           // [256,256] fp32
  float* out = (float*)d_out;

  const size_t MF = (size_t)BB * LL * DD;
  f16* Fp = (f16*)d_ws;   // 16 MiB each; ws = 64 MiB exactly
  f16* Fh = Fp + MF;
  f16* Vth = Fh + MF;     // hypotheses^T, fragment-order tiles
  f16* Vtp = Vth + MF;    // premises^T,   fragment-order tiles
  // WtF (131 KB) stashed in d_out tail: used only by proj, overwritten by flash
  f16* WtF = (f16*)((char*)d_out + (size_t)out_size * 4 - 256 * 256 * 2);

  // W -> fragment-order f16 W^T
  w_to_frag<<<dim3(8), 256, 0, stream>>>(W, WtF);
  // F = tanh(X @ W) + V^T emit (fragment-order)
  proj_mfma<<<dim3(512, 1, 2), 256, 0, stream>>>(premises, hypotheses, WtF, Fp,
                                                 Fh, Vtp, Vth);
  // betas (y=0) and alphas (y=1): 64 blocks/dir-quadrant -> 256 total
  flash_mfma<<<dim3(128, 2), 512, 0, stream>>>(Fp, Fh, Vth, Vtp, out);
}